// Round 2
// baseline (128.228 us; speedup 1.0000x reference)
//
#include <hip/hip_runtime.h>

// Problem constants (fixed by the reference module)
#define B_ 16
#define L_ 2048
#define D_ 128
#define GROUP_ 16
#define NG_ (L_ / GROUP_)   // 128

// Fast tanh: 1 - 2/(exp(2v)+1). Saturates correctly for |v| large
// (exp->inf => 1, exp->0 => -1). v_exp + v_rcp, ~1e-6 abs error.
__device__ __forceinline__ float tanh_fast(float v) {
    float e = __expf(2.0f * v);
    return 1.0f - 2.0f * __builtin_amdgcn_rcpf(e + 1.0f);
}

// One block per (b, g) group. 256 threads = 16 rows x 16 lanes/row,
// each thread owns 8 contiguous d-elements of its row in registers.
__global__ __launch_bounds__(256, 4) void ncn_kernel(
    const float* __restrict__ x,       // (B, L, D)
    const int*   __restrict__ gt,      // (B, L) permutation
    const int*   __restrict__ ctxlens, // (B,)
    const float* __restrict__ W,       // (2D,)
    const float* __restrict__ nalpha,  // (2,)
    const float* __restrict__ ngamma,  // (2D,)
    const float* __restrict__ nbeta,   // (2D,)
    float* __restrict__ out)           // (2, B, L, D) concat: yi_out, ya_out
{
    const int blk = blockIdx.x;
    const int b   = blk >> 7;      // / NG_
    const int g   = blk & (NG_ - 1);
    const int tid = threadIdx.x;
    const int row = tid >> 4;      // 0..15 (token within group)
    const int rl  = tid & 15;      // 0..15 (lane within row)
    const int d0  = rl << 3;       // 8 d-elements per thread

    __shared__ float s_xj[D_];
    __shared__ float s_sjW;

    const float a1 = nalpha[0];
    const float a2 = nalpha[1];

    // Per-chunk constants in registers (reused 16x)
    float Wi[8], Wj[8], g1v[8], b1v[8], g2v[8], b2v[8];
    *(float4*)&Wi[0]  = *(const float4*)(W + d0);
    *(float4*)&Wi[4]  = *(const float4*)(W + d0 + 4);
    *(float4*)&Wj[0]  = *(const float4*)(W + D_ + d0);
    *(float4*)&Wj[4]  = *(const float4*)(W + D_ + d0 + 4);
    *(float4*)&g1v[0] = *(const float4*)(ngamma + d0);
    *(float4*)&g1v[4] = *(const float4*)(ngamma + d0 + 4);
    *(float4*)&g2v[0] = *(const float4*)(ngamma + D_ + d0);
    *(float4*)&g2v[4] = *(const float4*)(ngamma + D_ + d0 + 4);
    *(float4*)&b1v[0] = *(const float4*)(nbeta + d0);
    *(float4*)&b1v[4] = *(const float4*)(nbeta + d0 + 4);
    *(float4*)&b2v[0] = *(const float4*)(nbeta + D_ + d0);
    *(float4*)&b2v[4] = *(const float4*)(nbeta + D_ + d0 + 4);

    // Gather this row's token
    const int l   = g * GROUP_ + row;
    const int tok = gt[b * L_ + l];
    const float* xp = x + ((size_t)(b * L_ + tok)) * D_ + d0;

    float xi[8], xa[8];
    *(float4*)&xi[0] = *(const float4*)xp;
    *(float4*)&xi[4] = *(const float4*)(xp + 4);
#pragma unroll
    for (int k = 0; k < 8; ++k) xa[k] = 0.0f;

    for (int j = 0; j < GROUP_; ++j) {
        // Row j publishes its current xi (the xj vector) and dot(xj, Wj)
        if (row == j) {
            *(float4*)&s_xj[d0]     = *(float4*)&xi[0];
            *(float4*)&s_xj[d0 + 4] = *(float4*)&xi[4];
            float p = 0.0f;
#pragma unroll
            for (int k = 0; k < 8; ++k) p = fmaf(xi[k], Wj[k], p);
            // reduce across the 16 lanes of this row (lane bits 0..3)
            p += __shfl_xor(p, 1);
            p += __shfl_xor(p, 2);
            p += __shfl_xor(p, 4);
            p += __shfl_xor(p, 8);
            if (rl == 0) s_sjW = p;
        }
        __syncthreads();

        // sim[row] = dot(xi[row], Wi) + dot(xj, Wj)
        float p = 0.0f;
#pragma unroll
        for (int k = 0; k < 8; ++k) p = fmaf(xi[k], Wi[k], p);
        p += __shfl_xor(p, 1);
        p += __shfl_xor(p, 2);
        p += __shfl_xor(p, 4);
        p += __shfl_xor(p, 8);
        const float sim = p + s_sjW;
        const float s2  = 0.5f * sim;   // (1-ALPHA) * sim, ALPHA = 0.5

        float xjv[8];
        *(float4*)&xjv[0] = *(const float4*)&s_xj[d0];
        *(float4*)&xjv[4] = *(const float4*)&s_xj[d0 + 4];

#pragma unroll
        for (int k = 0; k < 8; ++k) {
            float T  = fmaf(0.5f, xi[k], s2 * xjv[k]);   // ALPHA*xi + (1-ALPHA)*sim*xj
            float t1 = tanh_fast(a1 * T);
            float tn = fmaf(g1v[k], t1, b1v[k]);
            float Fv = (tn >= 0.0f) ? tn : 0.01f * tn;   // leaky relu
            xa[k] += Fv;
            float t2 = tanh_fast(a2 * xa[k]);
            xi[k] += fmaf(g2v[k], t2, b2v[k]);
        }
        __syncthreads();  // protect s_xj/s_sjW before next step's writer
    }

    // Validity mask (ctxlens): invalid groups output zeros
    const bool valid = (g * GROUP_) < ctxlens[b];
    if (!valid) {
#pragma unroll
        for (int k = 0; k < 8; ++k) { xi[k] = 0.0f; xa[k] = 0.0f; }
    }

    // Scatter back through the permutation (bijective -> every out elem written)
    float* o1 = out + ((size_t)(b * L_ + tok)) * D_ + d0;
    float* o2 = o1 + (size_t)B_ * L_ * D_;
    *(float4*)o1       = *(float4*)&xi[0];
    *(float4*)(o1 + 4) = *(float4*)&xi[4];
    *(float4*)o2       = *(float4*)&xa[0];
    *(float4*)(o2 + 4) = *(float4*)&xa[4];
}

extern "C" void kernel_launch(void* const* d_in, const int* in_sizes, int n_in,
                              void* d_out, int out_size, void* d_ws, size_t ws_size,
                              hipStream_t stream) {
    const float* x  = (const float*)d_in[0];
    const int*   gt = (const int*)d_in[1];
    const int*   cl = (const int*)d_in[2];
    const float* W  = (const float*)d_in[3];
    const float* na = (const float*)d_in[4];
    const float* ng = (const float*)d_in[5];
    const float* nb = (const float*)d_in[6];
    float* out = (float*)d_out;

    ncn_kernel<<<B_ * NG_, 256, 0, stream>>>(x, gt, cl, W, na, ng, nb, out);
}

// Round 4
// 123.530 us; speedup vs baseline: 1.0380x; 1.0380x over previous
//
#include <hip/hip_runtime.h>

// Problem constants (fixed by the reference module)
#define B_ 16
#define L_ 2048
#define D_ 128
#define GROUP_ 16
#define NG_ (L_ / GROUP_)   // 128

// One block per (b, g) group. 256 threads = 16 rows x 16 lanes/row,
// each thread owns 8 contiguous d-elements of its row in registers.
//
// tanh folding: g*tanh(a*T) + b == 2g * r + (b - g), r = 1/(1 + exp(-2a*T)).
// So we precompute G = 2g, Bm = b - g per element and per-tanh cost is
// mul, exp, add, rcp, fma (2 trans + 3 VALU).
__global__ __launch_bounds__(256, 4) void ncn_kernel(
    const float* __restrict__ x,       // (B, L, D)
    const int*   __restrict__ gt,      // (B, L) permutation
    const int*   __restrict__ ctxlens, // (B,)
    const float* __restrict__ W,       // (2D,)
    const float* __restrict__ nalpha,  // (2,)
    const float* __restrict__ ngamma,  // (2D,)
    const float* __restrict__ nbeta,   // (2D,)
    float* __restrict__ out)           // (2, B, L, D) concat: yi_out, ya_out
{
    const int blk = blockIdx.x;
    const int b   = blk >> 7;      // / NG_
    const int g   = blk & (NG_ - 1);
    const int tid = threadIdx.x;
    const int row = tid >> 4;      // 0..15 (token within group)
    const int rl  = tid & 15;      // 0..15 (lane within row)
    const int d0  = rl << 3;       // 8 d-elements per thread

    __shared__ float s_xj[2][D_];  // double-buffered broadcast row

    const float a1 = nalpha[0];
    const float a2 = nalpha[1];
    const float m1 = -2.0f * a1;   // exp(-2*a1*T)
    const float m2 = -2.0f * a2;

    // Per-chunk constants in registers (reused 16x). Folded forms.
    float Wi[8], Wj[8], G1[8], B1[8], G2[8], B2[8];
    {
        float g1r[8], b1r[8], g2r[8], b2r[8];
        *(float4*)&Wi[0]  = *(const float4*)(W + d0);
        *(float4*)&Wi[4]  = *(const float4*)(W + d0 + 4);
        *(float4*)&Wj[0]  = *(const float4*)(W + D_ + d0);
        *(float4*)&Wj[4]  = *(const float4*)(W + D_ + d0 + 4);
        *(float4*)&g1r[0] = *(const float4*)(ngamma + d0);
        *(float4*)&g1r[4] = *(const float4*)(ngamma + d0 + 4);
        *(float4*)&g2r[0] = *(const float4*)(ngamma + D_ + d0);
        *(float4*)&g2r[4] = *(const float4*)(ngamma + D_ + d0 + 4);
        *(float4*)&b1r[0] = *(const float4*)(nbeta + d0);
        *(float4*)&b1r[4] = *(const float4*)(nbeta + d0 + 4);
        *(float4*)&b2r[0] = *(const float4*)(nbeta + D_ + d0);
        *(float4*)&b2r[4] = *(const float4*)(nbeta + D_ + d0 + 4);
#pragma unroll
        for (int k = 0; k < 8; ++k) {
            G1[k] = 2.0f * g1r[k];
            B1[k] = b1r[k] - g1r[k];
            G2[k] = 2.0f * g2r[k];
            B2[k] = b2r[k] - g2r[k];
        }
    }
    // Pin loop-invariant constants in VGPRs: opaque def prevents the
    // compiler from sinking/rematerializing the global loads into the
    // j-loop (Round-2 showed VGPR=44 => consts were being re-fetched
    // every step, ~200-cyc latency chains).
#pragma unroll
    for (int k = 0; k < 8; ++k) {
        asm volatile("" : "+v"(Wi[k]));
        asm volatile("" : "+v"(Wj[k]));
        asm volatile("" : "+v"(G1[k]));
        asm volatile("" : "+v"(B1[k]));
        asm volatile("" : "+v"(G2[k]));
        asm volatile("" : "+v"(B2[k]));
    }

    // Gather this row's token
    const int l   = g * GROUP_ + row;
    const int tok = gt[b * L_ + l];
    const float* xp = x + ((size_t)(b * L_ + tok)) * D_ + d0;

    float xi[8], xa[8];
    *(float4*)&xi[0] = *(const float4*)xp;
    *(float4*)&xi[4] = *(const float4*)(xp + 4);
#pragma unroll
    for (int k = 0; k < 8; ++k) xa[k] = 0.0f;

    // Row 0 publishes its initial xi into buffer 0
    if (row == 0) {
        *(float4*)&s_xj[0][d0]     = *(float4*)&xi[0];
        *(float4*)&s_xj[0][d0 + 4] = *(float4*)&xi[4];
    }
    __syncthreads();

    for (int j = 0; j < GROUP_; ++j) {
        const int p = j & 1;

        float xjv[8];
        *(float4*)&xjv[0] = *(const float4*)&s_xj[p][d0];
        *(float4*)&xjv[4] = *(const float4*)&s_xj[p][d0 + 4];

        // sim[row] = dot(xi[row], Wi) + dot(xj, Wj): combined partial,
        // single 4-level shuffle reduce across the 16 lanes of this row.
        float s = 0.0f;
#pragma unroll
        for (int k = 0; k < 8; ++k) s = fmaf(xi[k], Wi[k], s);
#pragma unroll
        for (int k = 0; k < 8; ++k) s = fmaf(xjv[k], Wj[k], s);
        s += __shfl_xor(s, 1);
        s += __shfl_xor(s, 2);
        s += __shfl_xor(s, 4);
        s += __shfl_xor(s, 8);
        const float s2 = 0.5f * s;   // (1-ALPHA) * sim, ALPHA = 0.5

#pragma unroll
        for (int k = 0; k < 8; ++k) {
            float T  = fmaf(0.5f, xi[k], s2 * xjv[k]);   // ALPHA*xi + (1-ALPHA)*sim*xj
            float e1 = __expf(m1 * T);
            float r1 = __builtin_amdgcn_rcpf(1.0f + e1);
            float tn = fmaf(G1[k], r1, B1[k]);           // g1*tanh(a1*T) + b1
            float Fv = fmaxf(tn, 0.01f * tn);            // leaky relu
            xa[k] += Fv;
            float e2 = __expf(m2 * xa[k]);
            float r2 = __builtin_amdgcn_rcpf(1.0f + e2);
            xi[k] += fmaf(G2[k], r2, B2[k]);             // xi += g2*tanh(a2*xa) + b2
        }

        // Next step's broadcaster writes the OTHER buffer; the single
        // barrier at loop top orders both visibility and WAR reuse.
        if (j + 1 < GROUP_ && row == j + 1) {
            *(float4*)&s_xj[p ^ 1][d0]     = *(float4*)&xi[0];
            *(float4*)&s_xj[p ^ 1][d0 + 4] = *(float4*)&xi[4];
        }
        __syncthreads();
    }

    // Validity mask (ctxlens): invalid groups output zeros
    const bool valid = (g * GROUP_) < ctxlens[b];
    if (!valid) {
#pragma unroll
        for (int k = 0; k < 8; ++k) { xi[k] = 0.0f; xa[k] = 0.0f; }
    }

    // Scatter back through the permutation (bijective -> every out elem written)
    float* o1 = out + ((size_t)(b * L_ + tok)) * D_ + d0;
    float* o2 = o1 + (size_t)B_ * L_ * D_;
    *(float4*)o1       = *(float4*)&xi[0];
    *(float4*)(o1 + 4) = *(float4*)&xi[4];
    *(float4*)o2       = *(float4*)&xa[0];
    *(float4*)(o2 + 4) = *(float4*)&xa[4];
}

extern "C" void kernel_launch(void* const* d_in, const int* in_sizes, int n_in,
                              void* d_out, int out_size, void* d_ws, size_t ws_size,
                              hipStream_t stream) {
    const float* x  = (const float*)d_in[0];
    const int*   gt = (const int*)d_in[1];
    const int*   cl = (const int*)d_in[2];
    const float* W  = (const float*)d_in[3];
    const float* na = (const float*)d_in[4];
    const float* ng = (const float*)d_in[5];
    const float* nb = (const float*)d_in[6];
    float* out = (float*)d_out;

    ncn_kernel<<<B_ * NG_, 256, 0, stream>>>(x, gt, cl, W, na, ng, nb, out);
}

// Round 5
// 122.645 us; speedup vs baseline: 1.0455x; 1.0072x over previous
//
#include <hip/hip_runtime.h>

// Problem constants (fixed by the reference module)
#define B_ 16
#define L_ 2048
#define D_ 128
#define GROUP_ 16
#define NG_ (L_ / GROUP_)   // 128
#define LOG2E_ 1.44269504088896340736f

// DPP-based butterfly add within each 16-lane row (full-rate VALU, no LDS).
template<int CTRL>
__device__ __forceinline__ float dpp_add(float v) {
    int x = __builtin_amdgcn_update_dpp(0, __float_as_int(v), CTRL, 0xF, 0xF, false);
    return v + __int_as_float(x);
}
__device__ __forceinline__ float row16_sum(float v) {
    v = dpp_add<0xB1>(v);   // quad_perm(1,0,3,2)  ~ xor 1
    v = dpp_add<0x4E>(v);   // quad_perm(2,3,0,1)  ~ xor 2
    v = dpp_add<0x141>(v);  // row_half_mirror     ~ xor 4 (quad-uniform by now)
    v = dpp_add<0x140>(v);  // row_mirror          ~ xor 8 (8-group-uniform by now)
    return v;
}

// Batched reciprocal: r[k] = 1/d[k] for 8 values with ONE v_rcp (16-cyc trans)
// + 21 full-rate muls, instead of 8 v_rcp (128 cyc). Requires all d[k] finite.
__device__ __forceinline__ void rcp8(const float d[8], float r[8]) {
    float p[8];
    p[0] = d[0];
#pragma unroll
    for (int k = 1; k < 8; ++k) p[k] = p[k - 1] * d[k];
    float R = __builtin_amdgcn_rcpf(p[7]);
#pragma unroll
    for (int k = 7; k >= 1; --k) { r[k] = p[k - 1] * R; R *= d[k]; }
    r[0] = R;
}

// One block per (b,g) group. 256 threads = 16 rows x 16 lanes, 8 elems/thread.
// Trans-minimized form (Round-4 analysis: v_exp/v_rcp ~16 cyc wave64, the
// kernel is trans-issue-bound):
//   tanh(a*v) = 2*r - 1,  r = 1/(1 + exp2(c*v)),  c = -2a*log2e
//   g1*tanh(a1*T)+b1 scaled by S=-2*a2*log2e and accumulated as za = S*xa,
//   so exp2 of path 2 takes za directly (no mul). xa = za/S at epilogue.
__global__ __launch_bounds__(256, 4) void ncn_kernel(
    const float* __restrict__ x,       // (B, L, D)
    const int*   __restrict__ gt,      // (B, L) permutation
    const int*   __restrict__ ctxlens, // (B,)
    const float* __restrict__ W,       // (2D,)
    const float* __restrict__ nalpha,  // (2,)
    const float* __restrict__ ngamma,  // (2D,)
    const float* __restrict__ nbeta,   // (2D,)
    float* __restrict__ out)           // (2, B, L, D) concat: yi_out, ya_out
{
    const int blk = blockIdx.x;
    const int b   = blk >> 7;      // / NG_
    const int g   = blk & (NG_ - 1);
    const int tid = threadIdx.x;
    const int row = tid >> 4;      // 0..15 (token within group)
    const int rl  = tid & 15;      // 0..15 (lane within row)
    const int d0  = rl << 3;       // 8 d-elements per thread

    __shared__ float s_xj[2][D_];  // double-buffered broadcast row
    __shared__ float s_sjW[2];     // double-buffered dot(xj, Wj)

    const float a1 = nalpha[0];
    const float a2 = nalpha[1];
    const float ca = -a1 * LOG2E_;        // exp2 coefficient, path 1 (xi part)
    const float S  = -2.0f * a2 * LOG2E_; // za scale, path 2
    const bool  selMin = (S < 0.0f);      // leaky-relu under sign flip

    // Per-chunk constants in registers (reused 16x). Folded/pre-scaled forms.
    float Wi[8], Wj[8], G1S[8], B1S[8], G2[8], B2[8];
    {
        float g1r[8], b1r[8], g2r[8], b2r[8];
        *(float4*)&Wi[0]  = *(const float4*)(W + d0);
        *(float4*)&Wi[4]  = *(const float4*)(W + d0 + 4);
        *(float4*)&Wj[0]  = *(const float4*)(W + D_ + d0);
        *(float4*)&Wj[4]  = *(const float4*)(W + D_ + d0 + 4);
        *(float4*)&g1r[0] = *(const float4*)(ngamma + d0);
        *(float4*)&g1r[4] = *(const float4*)(ngamma + d0 + 4);
        *(float4*)&g2r[0] = *(const float4*)(ngamma + D_ + d0);
        *(float4*)&g2r[4] = *(const float4*)(ngamma + D_ + d0 + 4);
        *(float4*)&b1r[0] = *(const float4*)(nbeta + d0);
        *(float4*)&b1r[4] = *(const float4*)(nbeta + d0 + 4);
        *(float4*)&b2r[0] = *(const float4*)(nbeta + D_ + d0);
        *(float4*)&b2r[4] = *(const float4*)(nbeta + D_ + d0 + 4);
#pragma unroll
        for (int k = 0; k < 8; ++k) {
            G1S[k] = S * 2.0f * g1r[k];          // S*(2*g1)
            B1S[k] = S * (b1r[k] - g1r[k]);      // S*(b1-g1)
            G2[k]  = 2.0f * g2r[k];
            B2[k]  = b2r[k] - g2r[k];
        }
    }
#pragma unroll
    for (int k = 0; k < 8; ++k) {
        asm volatile("" : "+v"(Wi[k]));
        asm volatile("" : "+v"(Wj[k]));
        asm volatile("" : "+v"(G1S[k]));
        asm volatile("" : "+v"(B1S[k]));
        asm volatile("" : "+v"(G2[k]));
        asm volatile("" : "+v"(B2[k]));
    }

    // Gather this row's token
    const int l   = g * GROUP_ + row;
    const int tok = gt[b * L_ + l];
    const float* xp = x + ((size_t)(b * L_ + tok)) * D_ + d0;

    float xi[8], za[8];
    *(float4*)&xi[0] = *(const float4*)xp;
    *(float4*)&xi[4] = *(const float4*)(xp + 4);
#pragma unroll
    for (int k = 0; k < 8; ++k) za[k] = 0.0f;

    // Row 0 publishes its initial xi + its Wj-dot into buffer 0
    if (row == 0) {
        *(float4*)&s_xj[0][d0]     = *(float4*)&xi[0];
        *(float4*)&s_xj[0][d0 + 4] = *(float4*)&xi[4];
        float w = 0.0f;
#pragma unroll
        for (int k = 0; k < 8; ++k) w = fmaf(xi[k], Wj[k], w);
        w = row16_sum(w);
        if (rl == 0) s_sjW[0] = w;
    }

    for (int j = 0; j < GROUP_; ++j) {
        __syncthreads();           // orders previous publisher's writes
        const int p = j & 1;

        float xjv[8];
        *(float4*)&xjv[0] = *(const float4*)&s_xj[p][d0];
        *(float4*)&xjv[4] = *(const float4*)&s_xj[p][d0 + 4];
        const float sjW = s_sjW[p];   // broadcast read

        // sim[row] = dot(xi[row], Wi) + sjW (publisher precomputed Wj part)
        float s = 0.0f;
#pragma unroll
        for (int k = 0; k < 8; ++k) s = fmaf(xi[k], Wi[k], s);
        s = row16_sum(s);
        const float sim = s + sjW;
        const float cb  = ca * sim;   // = (-2*a1*log2e) * (0.5*sim)

        // Pass 1: all 8 sigmoid-denominators for tanh(a1*T), then batch rcp.
        float darr[8], r1[8];
#pragma unroll
        for (int k = 0; k < 8; ++k) {
            float u = fmaf(ca, xi[k], cb * xjv[k]);  // -2a1*log2e * T
            u = fminf(u, 15.0f);                     // no inf into the batch product
            darr[k] = 1.0f + __builtin_amdgcn_exp2f(u);
        }
        rcp8(darr, r1);

        // Pass 2: scaled leaky-relu accumulate, then path-2 denominators.
#pragma unroll
        for (int k = 0; k < 8; ++k) {
            float tnS = fmaf(G1S[k], r1[k], B1S[k]); // S*(g1*tanh+b1)
            float alt = 0.01f * tnS;
            float FvS = selMin ? fminf(tnS, alt) : fmaxf(tnS, alt);
            za[k] += FvS;                            // za = S * xa
            float z = fminf(za[k], 15.0f);
            darr[k] = 1.0f + __builtin_amdgcn_exp2f(z);
        }
        rcp8(darr, r1);

        // Pass 3: xi update
#pragma unroll
        for (int k = 0; k < 8; ++k)
            xi[k] += fmaf(G2[k], r1[k], B2[k]);

        // Next step's broadcaster publishes xj and its Wj-dot (other buffer).
        if (row == j + 1) {
            *(float4*)&s_xj[p ^ 1][d0]     = *(float4*)&xi[0];
            *(float4*)&s_xj[p ^ 1][d0 + 4] = *(float4*)&xi[4];
            float w = 0.0f;
#pragma unroll
            for (int k = 0; k < 8; ++k) w = fmaf(xi[k], Wj[k], w);
            w = row16_sum(w);
            if (rl == 0) s_sjW[p ^ 1] = w;
        }
    }

    // Recover xa = za / S; validity mask (ctxlens = L here, but keep correct)
    const float invS = 1.0f / S;
    float xa[8];
#pragma unroll
    for (int k = 0; k < 8; ++k) xa[k] = za[k] * invS;

    const bool valid = (g * GROUP_) < ctxlens[b];
    if (!valid) {
#pragma unroll
        for (int k = 0; k < 8; ++k) { xi[k] = 0.0f; xa[k] = 0.0f; }
    }

    // Scatter back through the permutation (bijective -> every out elem written)
    float* o1 = out + ((size_t)(b * L_ + tok)) * D_ + d0;
    float* o2 = o1 + (size_t)B_ * L_ * D_;
    *(float4*)o1       = *(float4*)&xi[0];
    *(float4*)(o1 + 4) = *(float4*)&xi[4];
    *(float4*)o2       = *(float4*)&xa[0];
    *(float4*)(o2 + 4) = *(float4*)&xa[4];
}

extern "C" void kernel_launch(void* const* d_in, const int* in_sizes, int n_in,
                              void* d_out, int out_size, void* d_ws, size_t ws_size,
                              hipStream_t stream) {
    const float* x  = (const float*)d_in[0];
    const int*   gt = (const int*)d_in[1];
    const int*   cl = (const int*)d_in[2];
    const float* W  = (const float*)d_in[3];
    const float* na = (const float*)d_in[4];
    const float* ng = (const float*)d_in[5];
    const float* nb = (const float*)d_in[6];
    float* out = (float*)d_out;

    ncn_kernel<<<B_ * NG_, 256, 0, stream>>>(x, gt, cl, W, na, ng, nb, out);
}